// Round 10
// baseline (532.352 us; speedup 1.0000x reference)
//
#include <hip/hip_runtime.h>
#include <hip/hip_bf16.h>
#include <math.h>

#define NN 100000
#define CC 128
#define EE 1600000
#define EPT 8                    // edges per thread in edge-chunk kernels
#define FCHUNK (256 * EPT)       // 2048 edges per block
#define NCHUNKS ((EE + FCHUNK - 1) / FCHUNK)  // 782
#define NB_E NCHUNKS             // edge chunks
#define WB 512                   // nodes per bucket (power of 2)
#define WSHIFT 9
#define NBUCK ((NN + WB - 1) / WB)  // 196

typedef short  bf16x8 __attribute__((ext_vector_type(8)));
typedef float  f32x4  __attribute__((ext_vector_type(4)));
typedef float  f32x4v __attribute__((ext_vector_type(4)));
typedef unsigned short u16x8 __attribute__((ext_vector_type(8)));

#define TP   136   // ushort stride for bf16 T rows (272 B)

__device__ __forceinline__ ushort f2bf(float f) {
    __hip_bfloat16 h = __float2bfloat16(f);   // RNE
    return __builtin_bit_cast(ushort, h);
}
__device__ __forceinline__ float bf2f(ushort u) {
    return __builtin_bit_cast(float, ((unsigned int)u) << 16);
}

// ===========================================================================
// CSR build via bucketed counting sort — ZERO global atomics. (proven R2/R7;
// R9's atomic-reservation variant was ~8us slower — reverted)
// ===========================================================================

__global__ void __launch_bounds__(256) bucket_hist(
    const int* __restrict__ dst, int* __restrict__ cnt)
{
    __shared__ int h[NBUCK];
    for (int i = threadIdx.x; i < NBUCK; i += 256) h[i] = 0;
    __syncthreads();
    int base = blockIdx.x * FCHUNK + threadIdx.x * EPT;
    if (base + EPT <= EE) {
        int4 d0 = *(const int4*)&dst[base];
        int4 d1 = *(const int4*)&dst[base + 4];
        int dd[8] = {d0.x, d0.y, d0.z, d0.w, d1.x, d1.y, d1.z, d1.w};
#pragma unroll
        for (int i = 0; i < 8; ++i) atomicAdd(&h[dd[i] >> WSHIFT], 1);
    } else {
        for (int i = 0; i < EPT; ++i) {
            int e = base + i;
            if (e < EE) atomicAdd(&h[dst[e] >> WSHIFT], 1);
        }
    }
    __syncthreads();
    for (int i = threadIdx.x; i < NBUCK; i += 256)
        cnt[i * NB_E + blockIdx.x] = h[i];
}

__global__ void __launch_bounds__(256) scan_cnt(
    int* __restrict__ cnt, int* __restrict__ total)
{
    __shared__ int wsum[4];
    int row = blockIdx.x;
    int* p = cnt + row * NB_E;
    int tid = threadIdx.x, lane = tid & 63, wid = tid >> 6;
    int v[4], s = 0;
#pragma unroll
    for (int j = 0; j < 4; ++j) {
        int idx = tid * 4 + j;
        v[j] = (idx < NB_E) ? p[idx] : 0;
        s += v[j];
    }
    int inc = s;
#pragma unroll
    for (int off = 1; off < 64; off <<= 1) {
        int n = __shfl_up(inc, off);
        if (lane >= off) inc += n;
    }
    if (lane == 63) wsum[wid] = inc;
    __syncthreads();
    int wofs = 0;
#pragma unroll
    for (int w = 0; w < 4; ++w)
        if (w < wid) wofs += wsum[w];
    int run = wofs + inc - s;
#pragma unroll
    for (int j = 0; j < 4; ++j) {
        int idx = tid * 4 + j;
        if (idx < NB_E) p[idx] = run;
        run += v[j];
    }
    if (tid == 255) total[row] = run;
}

__global__ void scan_base(const int* __restrict__ total,
                          int* __restrict__ bucketBase, int* __restrict__ rowptr)
{
    int lane = threadIdx.x;   // 64 threads
    int v[4], s = 0;
#pragma unroll
    for (int j = 0; j < 4; ++j) {
        int idx = lane * 4 + j;
        v[j] = (idx < NBUCK) ? total[idx] : 0;
        s += v[j];
    }
    int inc = s;
#pragma unroll
    for (int off = 1; off < 64; off <<= 1) {
        int n = __shfl_up(inc, off);
        if (lane >= off) inc += n;
    }
    int run = inc - s;
#pragma unroll
    for (int j = 0; j < 4; ++j) {
        int idx = lane * 4 + j;
        if (idx < NBUCK) bucketBase[idx] = run;
        run += v[j];
    }
    if (lane == 63) { bucketBase[NBUCK] = EE; rowptr[NN] = EE; }
}

__global__ void __launch_bounds__(256) bucket_scatter(
    const int* __restrict__ src, const int* __restrict__ dst,
    const int* __restrict__ cntEx, const int* __restrict__ bucketBase,
    unsigned int* __restrict__ pairs)
{
    __shared__ int h[NBUCK];
    __shared__ int bOfs[NBUCK];
    for (int i = threadIdx.x; i < NBUCK; i += 256) {
        h[i] = 0;
        bOfs[i] = bucketBase[i] + cntEx[i * NB_E + blockIdx.x];
    }
    __syncthreads();
    int base = blockIdx.x * FCHUNK + threadIdx.x * EPT;
    if (base + EPT <= EE) {
        int4 d0 = *(const int4*)&dst[base];
        int4 d1 = *(const int4*)&dst[base + 4];
        int4 s0 = *(const int4*)&src[base];
        int4 s1 = *(const int4*)&src[base + 4];
        int dd[8] = {d0.x, d0.y, d0.z, d0.w, d1.x, d1.y, d1.z, d1.w};
        int ss[8] = {s0.x, s0.y, s0.z, s0.w, s1.x, s1.y, s1.z, s1.w};
#pragma unroll
        for (int i = 0; i < 8; ++i) {
            int d = dd[i];
            int k = d >> WSHIFT;
            int r = atomicAdd(&h[k], 1);
            pairs[bOfs[k] + r] = ((unsigned)ss[i] << WSHIFT) | (unsigned)(d & (WB - 1));
        }
    } else {
        for (int i = 0; i < EPT; ++i) {
            int e = base + i;
            if (e < EE) {
                int d = dst[e];
                int k = d >> WSHIFT;
                int r = atomicAdd(&h[k], 1);
                pairs[bOfs[k] + r] = ((unsigned)src[e] << WSHIFT) | (unsigned)(d & (WB - 1));
            }
        }
    }
}

__global__ void __launch_bounds__(256) csr_build(
    const unsigned int* __restrict__ pairs, const int* __restrict__ bucketBase,
    int* __restrict__ rowptr, int* __restrict__ col)
{
    __shared__ int cnt[WB];
    __shared__ int ofs[WB];
    __shared__ int wsum[4];
    int k = blockIdx.x;
    int tid = threadIdx.x, lane = tid & 63, wid = tid >> 6;
    int nodeBase = k * WB;
    int nNodes = NN - nodeBase; if (nNodes > WB) nNodes = WB;
    for (int i = tid; i < WB; i += 256) cnt[i] = 0;
    __syncthreads();
    int beg = bucketBase[k], end = bucketBase[k + 1];
    for (int e = beg + tid; e < end; e += 256)
        atomicAdd(&cnt[pairs[e] & (WB - 1)], 1);
    __syncthreads();
    int a = cnt[2 * tid], b = cnt[2 * tid + 1];
    int s = a + b;
    int inc = s;
#pragma unroll
    for (int off = 1; off < 64; off <<= 1) {
        int n = __shfl_up(inc, off);
        if (lane >= off) inc += n;
    }
    if (lane == 63) wsum[wid] = inc;
    __syncthreads();
    int wofs = 0;
#pragma unroll
    for (int w = 0; w < 4; ++w)
        if (w < wid) wofs += wsum[w];
    int excl = wofs + inc - s;
    ofs[2 * tid] = excl;
    ofs[2 * tid + 1] = excl + a;
    __syncthreads();
    for (int i = tid; i < nNodes; i += 256)
        rowptr[nodeBase + i] = beg + ofs[i];
    __syncthreads();
    for (int e = beg + tid; e < end; e += 256) {
        unsigned p = pairs[e];
        int dl = p & (WB - 1);
        int r = atomicAdd(&ofs[dl], 1);
        col[beg + r] = (int)(p >> WSHIFT);
    }
}

// ===========================================================================
// Conversions
// ===========================================================================
__global__ void __launch_bounds__(256) convert_x_kernel(
    const float* __restrict__ x, ushort* __restrict__ xb)
{
    int i = blockIdx.x * 256 + threadIdx.x;   // float4 groups; NN*CC/4 total
    f32x4v v = __builtin_nontemporal_load((const f32x4v*)x + i);
    ushort4 o;
    o.x = f2bf(v[0]); o.y = f2bf(v[1]); o.z = f2bf(v[2]); o.w = f2bf(v[3]);
    ((ushort4*)xb)[i] = o;
}

__global__ void __launch_bounds__(256) convert_w6_kernel(
    const float* __restrict__ w0, const float* __restrict__ w1,
    const float* __restrict__ w2, const float* __restrict__ w3,
    const float* __restrict__ w4, const float* __restrict__ w5,
    ushort* __restrict__ wt)
{
    int i = blockIdx.x * 256 + threadIdx.x;  // 6*16384
    int mat = i >> 14;
    int rem = i & 16383;
    int k = rem >> 7, n = rem & 127;
    const float* w = (mat == 0) ? w0 : (mat == 1) ? w1 : (mat == 2) ? w2
                   : (mat == 3) ? w3 : (mat == 4) ? w4 : w5;
    wt[mat * 16384 + n * 128 + k] = f2bf(w[k * 128 + n]);
}

// ===========================================================================
// Gather (R7 proven form: 4-deep ILP, VGPR 32, occ 68%, 60.3us).
// R9's 8-deep probe REFUTED the concurrency hypothesis (62.9us) — the gather
// is service-rate-bound: FETCH ~188MB = 8 XCDs x 25.6MB table (each private
// L2 streams the whole table). This is the structural floor for this layout.
// ===========================================================================
__global__ void __launch_bounds__(256) gather_agg(
    const ushort* __restrict__ hin, const int* __restrict__ rowptr,
    const int* __restrict__ col, ushort* __restrict__ agg)
{
    const int grp    = threadIdx.x >> 4;            // 0..15
    const int lane16 = threadIdx.x & 15;
    const int gbase  = (threadIdx.x & 63) & 48;     // group base lane in wave
    const int n = blockIdx.x * 16 + grp;            // 6250*16 = 100000 exact
    const u16x8* hp = (const u16x8*)hin;

    u16x8 self = hp[n * 16 + lane16];
    float s0[8], s1[8], s2[8], s3[8];
#pragma unroll
    for (int k = 0; k < 8; ++k) {
        s0[k] = bf2f(self[k]); s1[k] = 0.f; s2[k] = 0.f; s3[k] = 0.f;
    }

    int beg = rowptr[n], end = rowptr[n + 1];
    while (beg < end) {
        int take = end - beg;
        if (take > 16) take = 16;
        int ci = (lane16 < take) ? col[beg + lane16] : 0;
        int j = 0;
        for (; j + 4 <= take; j += 4) {
            int n0 = __shfl(ci, gbase + j + 0);
            int n1 = __shfl(ci, gbase + j + 1);
            int n2 = __shfl(ci, gbase + j + 2);
            int n3 = __shfl(ci, gbase + j + 3);
            u16x8 a0 = hp[n0 * 16 + lane16];
            u16x8 a1 = hp[n1 * 16 + lane16];
            u16x8 a2 = hp[n2 * 16 + lane16];
            u16x8 a3 = hp[n3 * 16 + lane16];
#pragma unroll
            for (int k = 0; k < 8; ++k) {
                s0[k] += bf2f(a0[k]); s1[k] += bf2f(a1[k]);
                s2[k] += bf2f(a2[k]); s3[k] += bf2f(a3[k]);
            }
        }
        for (; j < take; ++j) {
            int n0 = __shfl(ci, gbase + j);
            u16x8 a0 = hp[n0 * 16 + lane16];
#pragma unroll
            for (int k = 0; k < 8; ++k) s0[k] += bf2f(a0[k]);
        }
        beg += take;
    }

    bf16x8 o;
#pragma unroll
    for (int k = 0; k < 8; ++k) o[k] = (short)f2bf(s0[k] + s1[k] + s2[k] + s3[k]);
    *(bf16x8*)&((ushort*)agg)[n * CC + lane16 * 8] = o;
}

// ===========================================================================
// MLP v8 — weights from GLOBAL (L2-resident broadcast; the MLP-phase of R8's
// fused kernel proved this path), LDS holds only T tiles + biases (36.4KB):
//  -> 2 blocks/CU at the proven (512,2)/128-VGPR envelope = 4 waves/SIMD,
//     2x the occupancy of the weight-LDS form (which needed 106KB -> 1 blk).
//  - non-persistent: 782 blocks, one 16-row tile per wave; no afn prefetch
//    registers; demand ~65 VGPR -> structurally no spill.
//  - keeps v7's no-spill discipline: nt-outer single f32x4 acc, retire to
//    LDS immediately, sched_barrier(0) at stage boundaries.
//  Weight L2 traffic ~400MB/layer @ 34.5TB/s ~ 12us; HBM fetch negligible
//  (64KB/matrix hot in every XCD's L2).
// ===========================================================================
template <bool FUSE_HEAD>
__global__ void __launch_bounds__(512, 2) mlp_tile(
    const ushort* __restrict__ hin,
    const ushort* __restrict__ waT, const float* __restrict__ ba,
    const ushort* __restrict__ wbT, const float* __restrict__ bb,
    ushort* __restrict__ hout,
    const float* __restrict__ lw, const float* __restrict__ lb,
    float* __restrict__ out)
{
    __shared__ ushort Tt[8][16 * TP];      // per-wave bf16 T tile
    __shared__ float  baS[CC], bbS[CC], lwS[CC];

    const int tid = threadIdx.x;
    if (tid < CC)                       baS[tid]           = ba[tid];
    else if (tid < 2 * CC)              bbS[tid - CC]      = bb[tid - CC];
    else if (FUSE_HEAD && tid < 3 * CC) lwS[tid - 2 * CC]  = lw[tid - 2 * CC];
    __syncthreads();

    const int wave = tid >> 6;
    const int lane = tid & 63;
    const int quad = lane >> 4;
    const int l16  = lane & 15;
    const int fq4  = quad * 4;

    const int wv = blockIdx.x * 8 + wave;
    if (wv >= NN / 16) return;
    const int wrow0 = wv * 16;
    ushort* Trow = &Tt[wave][l16 * TP];

    // A fragments (per-lane data doubles as B-frag of X^T)
    bf16x8 af[4];
#pragma unroll
    for (int kk = 0; kk < 4; ++kk)
        af[kk] = *(const bf16x8*)&hin[(wrow0 + l16) * CC + kk * 32 + quad * 8];

    // ---- stage 1 (swapped, nt-outer): one acc live at a time ----
#pragma unroll
    for (int nt = 0; nt < 8; ++nt) {
        f32x4 a = *(const f32x4*)&baS[nt * 16 + fq4];
#pragma unroll
        for (int kk = 0; kk < 4; ++kk) {
            bf16x8 wfrag = *(const bf16x8*)&waT[(nt * 16 + l16) * CC + kk * 32 + quad * 8];
            a = __builtin_amdgcn_mfma_f32_16x16x32_bf16(wfrag, af[kk], a, 0, 0, 0);
        }
        ushort4 pk;
        pk.x = f2bf(fmaxf(a[0], 0.f));
        pk.y = f2bf(fmaxf(a[1], 0.f));
        pk.z = f2bf(fmaxf(a[2], 0.f));
        pk.w = f2bf(fmaxf(a[3], 0.f));
        *(ushort4*)&Trow[nt * 16 + fq4] = pk;   // retire immediately
    }
    __builtin_amdgcn_sched_barrier(0);

    // ---- stage-2 fragments: lane reads its own T row (b128) ----
    bf16x8 tf[4];
#pragma unroll
    for (int kk = 0; kk < 4; ++kk)
        tf[kk] = *(const bf16x8*)&Trow[kk * 32 + quad * 8];
    __builtin_amdgcn_sched_barrier(0);

    // ---- stage 2 (swapped, nt-outer) ----
    if (FUSE_HEAD) {
        float part = 0.f;
#pragma unroll
        for (int nt = 0; nt < 8; ++nt) {
            f32x4 a2 = *(const f32x4*)&bbS[nt * 16 + fq4];
#pragma unroll
            for (int kk = 0; kk < 4; ++kk) {
                bf16x8 wfrag = *(const bf16x8*)&wbT[(nt * 16 + l16) * CC + kk * 32 + quad * 8];
                a2 = __builtin_amdgcn_mfma_f32_16x16x32_bf16(wfrag, tf[kk], a2, 0, 0, 0);
            }
            f32x4 lw4 = *(const f32x4*)&lwS[nt * 16 + fq4];
#pragma unroll
            for (int r = 0; r < 4; ++r) {
                float v = a2[r];
                v = v > 0.f ? v : expm1f(v);
                part += v * lw4[r];
            }
        }
        part += __shfl_xor(part, 16);
        part += __shfl_xor(part, 32);
        if (lane < 16) {
            float z = part + lb[0];
            out[wrow0 + l16] = 1.f / (1.f + expf(-z));
        }
    } else {
#pragma unroll
        for (int nt = 0; nt < 8; ++nt) {
            f32x4 a2 = *(const f32x4*)&bbS[nt * 16 + fq4];
#pragma unroll
            for (int kk = 0; kk < 4; ++kk) {
                bf16x8 wfrag = *(const bf16x8*)&wbT[(nt * 16 + l16) * CC + kk * 32 + quad * 8];
                a2 = __builtin_amdgcn_mfma_f32_16x16x32_bf16(wfrag, tf[kk], a2, 0, 0, 0);
            }
            ushort4 pk;
#pragma unroll
            for (int r = 0; r < 4; ++r) {
                float v = a2[r];
                v = v > 0.f ? v : expm1f(v);
                ((ushort*)&pk)[r] = f2bf(v);
            }
            *(ushort4*)&Trow[nt * 16 + fq4] = pk;
        }
        // coalesced 16B output stores (full-line writes)
#pragma unroll
        for (int i = 0; i < 4; ++i) {
            int r = i * 4 + quad;            // 0..15
            bf16x8 o = *(const bf16x8*)&Tt[wave][r * TP + l16 * 8];
            *(bf16x8*)&hout[(wrow0 + r) * CC + l16 * 8] = o;
        }
    }
}

extern "C" void kernel_launch(void* const* d_in, const int* in_sizes, int n_in,
                              void* d_out, int out_size, void* d_ws, size_t ws_size,
                              hipStream_t stream) {
    const float* x   = (const float*)d_in[0];
    const int*   ei  = (const int*)d_in[1];
    const int*   src = ei;
    const int*   dst = ei + EE;
    const float* w0a = (const float*)d_in[2];
    const float* b0a = (const float*)d_in[3];
    const float* w0b = (const float*)d_in[4];
    const float* b0b = (const float*)d_in[5];
    const float* w1a = (const float*)d_in[6];
    const float* b1a = (const float*)d_in[7];
    const float* w1b = (const float*)d_in[8];
    const float* b1b = (const float*)d_in[9];
    const float* w2a = (const float*)d_in[10];
    const float* b2a = (const float*)d_in[11];
    const float* w2b = (const float*)d_in[12];
    const float* b2b = (const float*)d_in[13];
    const float* lw  = (const float*)d_in[14];
    const float* lb  = (const float*)d_in[15];
    float* outp = (float*)d_out;

    // workspace layout (xb reused as layer-2 output)
    ushort* xb  = (ushort*)d_ws;                      // N*CC bf16
    ushort* hbA = xb + (size_t)NN * CC;               // N*CC bf16
    ushort* agg = hbA + (size_t)NN * CC;              // N*CC bf16
    ushort* wT  = agg + (size_t)NN * CC;              // 6 * 128*128 bf16
    int* col    = (int*)(wT + 6 * CC * CC);           // EE
    int* rowptr = col + EE;                           // NN+1

    // CSR-build temporaries alias agg (dead until the first gather)
    unsigned int* pairs = (unsigned int*)agg;
    int* cnt        = (int*)(pairs + EE);
    int* total      = cnt + NBUCK * NB_E;
    int* bucketBase = total + NBUCK;                  // NBUCK+1

    ushort* w0aT = wT;
    ushort* w0bT = wT + 1 * CC * CC;
    ushort* w1aT = wT + 2 * CC * CC;
    ushort* w1bT = wT + 3 * CC * CC;
    ushort* w2aT = wT + 4 * CC * CC;
    ushort* w2bT = wT + 5 * CC * CC;

    const int gatherBlocks = NN / 16;                 // 6250
    const int mlpBlocks    = (NN / 16 + 7) / 8;       // 782
    const int cvtXBlocks   = (NN * CC / 4) / 256;     // 12500

    // ---- conversions ----
    convert_x_kernel<<<cvtXBlocks, 256, 0, stream>>>(x, xb);
    convert_w6_kernel<<<6 * 64, 256, 0, stream>>>(w0a, w0b, w1a, w1b, w2a, w2b, wT);

    // ---- CSR build (bucketed counting sort, no global atomics) ----
    bucket_hist<<<NB_E, 256, 0, stream>>>(dst, cnt);
    scan_cnt<<<NBUCK, 256, 0, stream>>>(cnt, total);
    scan_base<<<1, 64, 0, stream>>>(total, bucketBase, rowptr);
    bucket_scatter<<<NB_E, 256, 0, stream>>>(src, dst, cnt, bucketBase, pairs);
    csr_build<<<NBUCK, 256, 0, stream>>>(pairs, bucketBase, rowptr, col);

    // ---- layer 1 ----
    gather_agg<<<gatherBlocks, 256, 0, stream>>>(xb, rowptr, col, agg);
    mlp_tile<false><<<mlpBlocks, 512, 0, stream>>>(agg, w0aT, b0a, w0bT, b0b, hbA,
                                                   nullptr, nullptr, nullptr);
    // ---- layer 2 (output into xb) ----
    gather_agg<<<gatherBlocks, 256, 0, stream>>>(hbA, rowptr, col, agg);
    mlp_tile<false><<<mlpBlocks, 512, 0, stream>>>(agg, w1aT, b1a, w1bT, b1b, xb,
                                                   nullptr, nullptr, nullptr);
    // ---- layer 3 + fused head ----
    gather_agg<<<gatherBlocks, 256, 0, stream>>>(xb, rowptr, col, agg);
    mlp_tile<true><<<mlpBlocks, 512, 0, stream>>>(agg, w2aT, b2a, w2bT, b2b, nullptr,
                                                  lw, lb, outp);
}

// Round 11
// 403.824 us; speedup vs baseline: 1.3183x; 1.3183x over previous
//
#include <hip/hip_runtime.h>
#include <hip/hip_bf16.h>
#include <math.h>

#define NN 100000
#define CC 128
#define EE 1600000
#define EPT 8                    // edges per thread in edge-chunk kernels
#define FCHUNK (256 * EPT)       // 2048 edges per block
#define NCHUNKS ((EE + FCHUNK - 1) / FCHUNK)  // 782
#define NB_E NCHUNKS             // edge chunks
#define WB 512                   // nodes per bucket (power of 2)
#define WSHIFT 9
#define NBUCK ((NN + WB - 1) / WB)  // 196

typedef short  bf16x8 __attribute__((ext_vector_type(8)));
typedef float  f32x4  __attribute__((ext_vector_type(4)));
typedef float  f32x4v __attribute__((ext_vector_type(4)));
typedef unsigned short u16x8 __attribute__((ext_vector_type(8)));

#define WPAD 136   // ushort stride for LDS weight rows (272 B)
#define TP   136   // ushort stride for bf16 T rows (272 B)
#define MLPB 256   // persistent MLP blocks (1 per CU)
#define MLPW 16    // waves per MLP block (1024 thr): 4 waves/SIMD at 1 block/CU

__device__ __forceinline__ ushort f2bf(float f) {
    __hip_bfloat16 h = __float2bfloat16(f);   // RNE
    return __builtin_bit_cast(ushort, h);
}
__device__ __forceinline__ float bf2f(ushort u) {
    return __builtin_bit_cast(float, ((unsigned int)u) << 16);
}

// ===========================================================================
// CSR build via bucketed counting sort — ZERO global atomics. (proven R2/R7)
// ===========================================================================

__global__ void __launch_bounds__(256) bucket_hist(
    const int* __restrict__ dst, int* __restrict__ cnt)
{
    __shared__ int h[NBUCK];
    for (int i = threadIdx.x; i < NBUCK; i += 256) h[i] = 0;
    __syncthreads();
    int base = blockIdx.x * FCHUNK + threadIdx.x * EPT;
    if (base + EPT <= EE) {
        int4 d0 = *(const int4*)&dst[base];
        int4 d1 = *(const int4*)&dst[base + 4];
        int dd[8] = {d0.x, d0.y, d0.z, d0.w, d1.x, d1.y, d1.z, d1.w};
#pragma unroll
        for (int i = 0; i < 8; ++i) atomicAdd(&h[dd[i] >> WSHIFT], 1);
    } else {
        for (int i = 0; i < EPT; ++i) {
            int e = base + i;
            if (e < EE) atomicAdd(&h[dst[e] >> WSHIFT], 1);
        }
    }
    __syncthreads();
    for (int i = threadIdx.x; i < NBUCK; i += 256)
        cnt[i * NB_E + blockIdx.x] = h[i];
}

__global__ void __launch_bounds__(256) scan_cnt(
    int* __restrict__ cnt, int* __restrict__ total)
{
    __shared__ int wsum[4];
    int row = blockIdx.x;
    int* p = cnt + row * NB_E;
    int tid = threadIdx.x, lane = tid & 63, wid = tid >> 6;
    int v[4], s = 0;
#pragma unroll
    for (int j = 0; j < 4; ++j) {
        int idx = tid * 4 + j;
        v[j] = (idx < NB_E) ? p[idx] : 0;
        s += v[j];
    }
    int inc = s;
#pragma unroll
    for (int off = 1; off < 64; off <<= 1) {
        int n = __shfl_up(inc, off);
        if (lane >= off) inc += n;
    }
    if (lane == 63) wsum[wid] = inc;
    __syncthreads();
    int wofs = 0;
#pragma unroll
    for (int w = 0; w < 4; ++w)
        if (w < wid) wofs += wsum[w];
    int run = wofs + inc - s;
#pragma unroll
    for (int j = 0; j < 4; ++j) {
        int idx = tid * 4 + j;
        if (idx < NB_E) p[idx] = run;
        run += v[j];
    }
    if (tid == 255) total[row] = run;
}

__global__ void scan_base(const int* __restrict__ total,
                          int* __restrict__ bucketBase, int* __restrict__ rowptr)
{
    int lane = threadIdx.x;   // 64 threads
    int v[4], s = 0;
#pragma unroll
    for (int j = 0; j < 4; ++j) {
        int idx = lane * 4 + j;
        v[j] = (idx < NBUCK) ? total[idx] : 0;
        s += v[j];
    }
    int inc = s;
#pragma unroll
    for (int off = 1; off < 64; off <<= 1) {
        int n = __shfl_up(inc, off);
        if (lane >= off) inc += n;
    }
    int run = inc - s;
#pragma unroll
    for (int j = 0; j < 4; ++j) {
        int idx = lane * 4 + j;
        if (idx < NBUCK) bucketBase[idx] = run;
        run += v[j];
    }
    if (lane == 63) { bucketBase[NBUCK] = EE; rowptr[NN] = EE; }
}

__global__ void __launch_bounds__(256) bucket_scatter(
    const int* __restrict__ src, const int* __restrict__ dst,
    const int* __restrict__ cntEx, const int* __restrict__ bucketBase,
    unsigned int* __restrict__ pairs)
{
    __shared__ int h[NBUCK];
    __shared__ int bOfs[NBUCK];
    for (int i = threadIdx.x; i < NBUCK; i += 256) {
        h[i] = 0;
        bOfs[i] = bucketBase[i] + cntEx[i * NB_E + blockIdx.x];
    }
    __syncthreads();
    int base = blockIdx.x * FCHUNK + threadIdx.x * EPT;
    if (base + EPT <= EE) {
        int4 d0 = *(const int4*)&dst[base];
        int4 d1 = *(const int4*)&dst[base + 4];
        int4 s0 = *(const int4*)&src[base];
        int4 s1 = *(const int4*)&src[base + 4];
        int dd[8] = {d0.x, d0.y, d0.z, d0.w, d1.x, d1.y, d1.z, d1.w};
        int ss[8] = {s0.x, s0.y, s0.z, s0.w, s1.x, s1.y, s1.z, s1.w};
#pragma unroll
        for (int i = 0; i < 8; ++i) {
            int d = dd[i];
            int k = d >> WSHIFT;
            int r = atomicAdd(&h[k], 1);
            pairs[bOfs[k] + r] = ((unsigned)ss[i] << WSHIFT) | (unsigned)(d & (WB - 1));
        }
    } else {
        for (int i = 0; i < EPT; ++i) {
            int e = base + i;
            if (e < EE) {
                int d = dst[e];
                int k = d >> WSHIFT;
                int r = atomicAdd(&h[k], 1);
                pairs[bOfs[k] + r] = ((unsigned)src[e] << WSHIFT) | (unsigned)(d & (WB - 1));
            }
        }
    }
}

__global__ void __launch_bounds__(256) csr_build(
    const unsigned int* __restrict__ pairs, const int* __restrict__ bucketBase,
    int* __restrict__ rowptr, int* __restrict__ col)
{
    __shared__ int cnt[WB];
    __shared__ int ofs[WB];
    __shared__ int wsum[4];
    int k = blockIdx.x;
    int tid = threadIdx.x, lane = tid & 63, wid = tid >> 6;
    int nodeBase = k * WB;
    int nNodes = NN - nodeBase; if (nNodes > WB) nNodes = WB;
    for (int i = tid; i < WB; i += 256) cnt[i] = 0;
    __syncthreads();
    int beg = bucketBase[k], end = bucketBase[k + 1];
    for (int e = beg + tid; e < end; e += 256)
        atomicAdd(&cnt[pairs[e] & (WB - 1)], 1);
    __syncthreads();
    int a = cnt[2 * tid], b = cnt[2 * tid + 1];
    int s = a + b;
    int inc = s;
#pragma unroll
    for (int off = 1; off < 64; off <<= 1) {
        int n = __shfl_up(inc, off);
        if (lane >= off) inc += n;
    }
    if (lane == 63) wsum[wid] = inc;
    __syncthreads();
    int wofs = 0;
#pragma unroll
    for (int w = 0; w < 4; ++w)
        if (w < wid) wofs += wsum[w];
    int excl = wofs + inc - s;
    ofs[2 * tid] = excl;
    ofs[2 * tid + 1] = excl + a;
    __syncthreads();
    for (int i = tid; i < nNodes; i += 256)
        rowptr[nodeBase + i] = beg + ofs[i];
    __syncthreads();
    for (int e = beg + tid; e < end; e += 256) {
        unsigned p = pairs[e];
        int dl = p & (WB - 1);
        int r = atomicAdd(&ofs[dl], 1);
        col[beg + r] = (int)(p >> WSHIFT);
    }
}

// ===========================================================================
// Conversions
// ===========================================================================
__global__ void __launch_bounds__(256) convert_x_kernel(
    const float* __restrict__ x, ushort* __restrict__ xb)
{
    int i = blockIdx.x * 256 + threadIdx.x;   // float4 groups; NN*CC/4 total
    f32x4v v = __builtin_nontemporal_load((const f32x4v*)x + i);
    ushort4 o;
    o.x = f2bf(v[0]); o.y = f2bf(v[1]); o.z = f2bf(v[2]); o.w = f2bf(v[3]);
    ((ushort4*)xb)[i] = o;
}

__global__ void __launch_bounds__(256) convert_w6_kernel(
    const float* __restrict__ w0, const float* __restrict__ w1,
    const float* __restrict__ w2, const float* __restrict__ w3,
    const float* __restrict__ w4, const float* __restrict__ w5,
    ushort* __restrict__ wt)
{
    int i = blockIdx.x * 256 + threadIdx.x;  // 6*16384
    int mat = i >> 14;
    int rem = i & 16383;
    int k = rem >> 7, n = rem & 127;
    const float* w = (mat == 0) ? w0 : (mat == 1) ? w1 : (mat == 2) ? w2
                   : (mat == 3) ? w3 : (mat == 4) ? w4 : w5;
    wt[mat * 16384 + n * 128 + k] = f2bf(w[k * 128 + n]);
}

// ===========================================================================
// Gather (R7 proven form: 4-deep ILP, VGPR 32, occ 68%, 60.3us). At the
// 8-XCD service floor (FETCH ~188MB = 8 x 25.6MB table); 8-deep refuted R9.
// ===========================================================================
__global__ void __launch_bounds__(256) gather_agg(
    const ushort* __restrict__ hin, const int* __restrict__ rowptr,
    const int* __restrict__ col, ushort* __restrict__ agg)
{
    const int grp    = threadIdx.x >> 4;            // 0..15
    const int lane16 = threadIdx.x & 15;
    const int gbase  = (threadIdx.x & 63) & 48;     // group base lane in wave
    const int n = blockIdx.x * 16 + grp;            // 6250*16 = 100000 exact
    const u16x8* hp = (const u16x8*)hin;

    u16x8 self = hp[n * 16 + lane16];
    float s0[8], s1[8], s2[8], s3[8];
#pragma unroll
    for (int k = 0; k < 8; ++k) {
        s0[k] = bf2f(self[k]); s1[k] = 0.f; s2[k] = 0.f; s3[k] = 0.f;
    }

    int beg = rowptr[n], end = rowptr[n + 1];
    while (beg < end) {
        int take = end - beg;
        if (take > 16) take = 16;
        int ci = (lane16 < take) ? col[beg + lane16] : 0;
        int j = 0;
        for (; j + 4 <= take; j += 4) {
            int n0 = __shfl(ci, gbase + j + 0);
            int n1 = __shfl(ci, gbase + j + 1);
            int n2 = __shfl(ci, gbase + j + 2);
            int n3 = __shfl(ci, gbase + j + 3);
            u16x8 a0 = hp[n0 * 16 + lane16];
            u16x8 a1 = hp[n1 * 16 + lane16];
            u16x8 a2 = hp[n2 * 16 + lane16];
            u16x8 a3 = hp[n3 * 16 + lane16];
#pragma unroll
            for (int k = 0; k < 8; ++k) {
                s0[k] += bf2f(a0[k]); s1[k] += bf2f(a1[k]);
                s2[k] += bf2f(a2[k]); s3[k] += bf2f(a3[k]);
            }
        }
        for (; j < take; ++j) {
            int n0 = __shfl(ci, gbase + j);
            u16x8 a0 = hp[n0 * 16 + lane16];
#pragma unroll
            for (int k = 0; k < 8; ++k) s0[k] += bf2f(a0[k]);
        }
        beg += take;
    }

    bf16x8 o;
#pragma unroll
    for (int k = 0; k < 8; ++k) o[k] = (short)f2bf(s0[k] + s1[k] + s2[k] + s3[k]);
    *(bf16x8*)&((ushort*)agg)[n * CC + lane16 * 8] = o;
}

// ===========================================================================
// MLP v9 = v7's LDS-weight nt-outer structure x 2x occupancy.
// R10 facts: (a) global-weight path is latency-bound (67us vs v7's 29 —
// ds_read 12cyc beats L2 200cyc); (b) the nt-outer body's NATURAL VGPR
// demand is 64 (compiler chose 64 under a 128 cap, zero spill).
// => the big-block geometry is now safe: 1024 thr / 16 waves share the
// 69.6KB weight staging; __launch_bounds__(1024,2) caps VGPR at 64 =
// exactly the proven demand. afn prefetch dropped (would need ~80 VGPR);
// 4 waves/SIMD TLP replaces it. LDS: 69632 + 16*4352 + 1536 = 140800 B
// -> 1 block/CU = 4 waves/SIMD (2x v7).
// ===========================================================================
template <bool FUSE_HEAD>
__global__ void __launch_bounds__(1024, 2) mlp_persist(
    const ushort* __restrict__ hin,
    const ushort* __restrict__ waT, const float* __restrict__ ba,
    const ushort* __restrict__ wbT, const float* __restrict__ bb,
    ushort* __restrict__ hout,
    const float* __restrict__ lw, const float* __restrict__ lb,
    float* __restrict__ out)
{
    __shared__ ushort WaS[CC * WPAD];      // [n][k], row stride 136
    __shared__ ushort WbS[CC * WPAD];
    __shared__ ushort Tt[MLPW][16 * TP];   // per-wave bf16 T tile
    __shared__ float  baS[CC], bbS[CC], lwS[CC];

    const int tid = threadIdx.x;

    for (int i = tid; i < CC * 16; i += 1024) {        // 2 iters/thread
        int row = i >> 4, ch = i & 15;
        *(bf16x8*)&WaS[row * WPAD + ch * 8] = *(const bf16x8*)&waT[row * CC + ch * 8];
        *(bf16x8*)&WbS[row * WPAD + ch * 8] = *(const bf16x8*)&wbT[row * CC + ch * 8];
    }
    if (tid < CC)                       baS[tid]           = ba[tid];
    else if (tid < 2 * CC)              bbS[tid - CC]      = bb[tid - CC];
    else if (FUSE_HEAD && tid < 3 * CC) lwS[tid - 2 * CC]  = lw[tid - 2 * CC];
    __syncthreads();

    const int wave = tid >> 6;
    const int lane = tid & 63;
    const int quad = lane >> 4;
    const int l16  = lane & 15;
    ushort* T = Tt[wave];
    const int nTiles = NN / 16;            // 6250
    const int stride = MLPB * MLPW;        // 4096
    const int fq4 = quad * 4;
    float lbv = FUSE_HEAD ? lb[0] : 0.f;
    ushort* Trow = &T[l16 * TP];

    for (int wv = blockIdx.x * MLPW + wave; wv < nTiles; wv += stride) {
        const int wrow0 = wv * 16;

        // A fragments (per-lane data doubles as B-frag of X^T)
        bf16x8 af[4];
#pragma unroll
        for (int kk = 0; kk < 4; ++kk)
            af[kk] = *(const bf16x8*)&hin[(wrow0 + l16) * CC + kk * 32 + quad * 8];

        // ---- stage 1 (swapped, nt-outer): one acc live at a time ----
#pragma unroll
        for (int nt = 0; nt < 8; ++nt) {
            f32x4 a = *(const f32x4*)&baS[nt * 16 + fq4];
#pragma unroll
            for (int kk = 0; kk < 4; ++kk) {
                bf16x8 wfrag = *(const bf16x8*)&WaS[(nt * 16 + l16) * WPAD + kk * 32 + quad * 8];
                a = __builtin_amdgcn_mfma_f32_16x16x32_bf16(wfrag, af[kk], a, 0, 0, 0);
            }
            ushort4 pk;
            pk.x = f2bf(fmaxf(a[0], 0.f));
            pk.y = f2bf(fmaxf(a[1], 0.f));
            pk.z = f2bf(fmaxf(a[2], 0.f));
            pk.w = f2bf(fmaxf(a[3], 0.f));
            *(ushort4*)&Trow[nt * 16 + fq4] = pk;   // retire immediately
        }
        __builtin_amdgcn_sched_barrier(0);

        // ---- stage-2 fragments: lane reads its own T row (b128) ----
        bf16x8 tf[4];
#pragma unroll
        for (int kk = 0; kk < 4; ++kk)
            tf[kk] = *(const bf16x8*)&Trow[kk * 32 + quad * 8];
        __builtin_amdgcn_sched_barrier(0);

        // ---- stage 2 (swapped, nt-outer) ----
        if (FUSE_HEAD) {
            float part = 0.f;
#pragma unroll
            for (int nt = 0; nt < 8; ++nt) {
                f32x4 a2 = *(const f32x4*)&bbS[nt * 16 + fq4];
#pragma unroll
                for (int kk = 0; kk < 4; ++kk) {
                    bf16x8 wfrag = *(const bf16x8*)&WbS[(nt * 16 + l16) * WPAD + kk * 32 + quad * 8];
                    a2 = __builtin_amdgcn_mfma_f32_16x16x32_bf16(wfrag, tf[kk], a2, 0, 0, 0);
                }
                f32x4 lw4 = *(const f32x4*)&lwS[nt * 16 + fq4];
#pragma unroll
                for (int r = 0; r < 4; ++r) {
                    float v = a2[r];
                    v = v > 0.f ? v : expm1f(v);
                    part += v * lw4[r];
                }
            }
            part += __shfl_xor(part, 16);
            part += __shfl_xor(part, 32);
            if (lane < 16) {
                float z = part + lbv;
                out[wrow0 + l16] = 1.f / (1.f + expf(-z));
            }
        } else {
#pragma unroll
            for (int nt = 0; nt < 8; ++nt) {
                f32x4 a2 = *(const f32x4*)&bbS[nt * 16 + fq4];
#pragma unroll
                for (int kk = 0; kk < 4; ++kk) {
                    bf16x8 wfrag = *(const bf16x8*)&WbS[(nt * 16 + l16) * WPAD + kk * 32 + quad * 8];
                    a2 = __builtin_amdgcn_mfma_f32_16x16x32_bf16(wfrag, tf[kk], a2, 0, 0, 0);
                }
                ushort4 pk;
#pragma unroll
                for (int r = 0; r < 4; ++r) {
                    float v = a2[r];
                    v = v > 0.f ? v : expm1f(v);
                    ((ushort*)&pk)[r] = f2bf(v);
                }
                *(ushort4*)&Trow[nt * 16 + fq4] = pk;
            }
            // coalesced 16B output stores (full-line writes)
#pragma unroll
            for (int i = 0; i < 4; ++i) {
                int r = i * 4 + quad;            // 0..15
                bf16x8 o = *(const bf16x8*)&T[r * TP + l16 * 8];
                *(bf16x8*)&hout[(wrow0 + r) * CC + l16 * 8] = o;
            }
        }
    }
}

extern "C" void kernel_launch(void* const* d_in, const int* in_sizes, int n_in,
                              void* d_out, int out_size, void* d_ws, size_t ws_size,
                              hipStream_t stream) {
    const float* x   = (const float*)d_in[0];
    const int*   ei  = (const int*)d_in[1];
    const int*   src = ei;
    const int*   dst = ei + EE;
    const float* w0a = (const float*)d_in[2];
    const float* b0a = (const float*)d_in[3];
    const float* w0b = (const float*)d_in[4];
    const float* b0b = (const float*)d_in[5];
    const float* w1a = (const float*)d_in[6];
    const float* b1a = (const float*)d_in[7];
    const float* w1b = (const float*)d_in[8];
    const float* b1b = (const float*)d_in[9];
    const float* w2a = (const float*)d_in[10];
    const float* b2a = (const float*)d_in[11];
    const float* w2b = (const float*)d_in[12];
    const float* b2b = (const float*)d_in[13];
    const float* lw  = (const float*)d_in[14];
    const float* lb  = (const float*)d_in[15];
    float* outp = (float*)d_out;

    // workspace layout (xb reused as layer-2 output)
    ushort* xb  = (ushort*)d_ws;                      // N*CC bf16
    ushort* hbA = xb + (size_t)NN * CC;               // N*CC bf16
    ushort* agg = hbA + (size_t)NN * CC;              // N*CC bf16
    ushort* wT  = agg + (size_t)NN * CC;              // 6 * 128*128 bf16
    int* col    = (int*)(wT + 6 * CC * CC);           // EE
    int* rowptr = col + EE;                           // NN+1

    // CSR-build temporaries alias agg (dead until the first gather)
    unsigned int* pairs = (unsigned int*)agg;
    int* cnt        = (int*)(pairs + EE);
    int* total      = cnt + NBUCK * NB_E;
    int* bucketBase = total + NBUCK;                  // NBUCK+1

    ushort* w0aT = wT;
    ushort* w0bT = wT + 1 * CC * CC;
    ushort* w1aT = wT + 2 * CC * CC;
    ushort* w1bT = wT + 3 * CC * CC;
    ushort* w2aT = wT + 4 * CC * CC;
    ushort* w2bT = wT + 5 * CC * CC;

    const int gatherBlocks = NN / 16;                 // 6250
    const int cvtXBlocks   = (NN * CC / 4) / 256;     // 12500

    // ---- conversions ----
    convert_x_kernel<<<cvtXBlocks, 256, 0, stream>>>(x, xb);
    convert_w6_kernel<<<6 * 64, 256, 0, stream>>>(w0a, w0b, w1a, w1b, w2a, w2b, wT);

    // ---- CSR build (bucketed counting sort, no global atomics) ----
    bucket_hist<<<NB_E, 256, 0, stream>>>(dst, cnt);
    scan_cnt<<<NBUCK, 256, 0, stream>>>(cnt, total);
    scan_base<<<1, 64, 0, stream>>>(total, bucketBase, rowptr);
    bucket_scatter<<<NB_E, 256, 0, stream>>>(src, dst, cnt, bucketBase, pairs);
    csr_build<<<NBUCK, 256, 0, stream>>>(pairs, bucketBase, rowptr, col);

    // ---- layer 1 ----
    gather_agg<<<gatherBlocks, 256, 0, stream>>>(xb, rowptr, col, agg);
    mlp_persist<false><<<MLPB, 1024, 0, stream>>>(agg, w0aT, b0a, w0bT, b0b, hbA,
                                                  nullptr, nullptr, nullptr);
    // ---- layer 2 (output into xb) ----
    gather_agg<<<gatherBlocks, 256, 0, stream>>>(hbA, rowptr, col, agg);
    mlp_persist<false><<<MLPB, 1024, 0, stream>>>(agg, w1aT, b1a, w1bT, b1b, xb,
                                                  nullptr, nullptr, nullptr);
    // ---- layer 3 + fused head ----
    gather_agg<<<gatherBlocks, 256, 0, stream>>>(xb, rowptr, col, agg);
    mlp_persist<true><<<MLPB, 1024, 0, stream>>>(agg, w2aT, b2a, w2bT, b2b, nullptr,
                                                 lw, lb, outp);
}